// Round 10
// baseline (15177.539 us; speedup 1.0000x reference)
//
#include <hip/hip_runtime.h>
#include <hip/hip_cooperative_groups.h>

namespace cg = cooperative_groups;

#define B_ 128
#define T_ 256
#define F_ 128
#define H_ 768
#define NG 3072      // 4*H
#define BM 32
#define BN 64
#define BK 128
#define UPT 16       // units per N-tile = BN/4
#define NB 200       // decoder cooperative grid

typedef short s16x8 __attribute__((ext_vector_type(8)));
typedef float f32x4 __attribute__((ext_vector_type(4)));

__device__ __forceinline__ unsigned short f2bf(float x) {
  unsigned u = __float_as_uint(x);
  u += 0x7fffu + ((u >> 16) & 1u);
  return (unsigned short)(u >> 16);
}

__device__ __forceinline__ void async16(const void* g, void* l) {
  __builtin_amdgcn_global_load_lds(
      (const __attribute__((address_space(1))) void*)g,
      (__attribute__((address_space(3))) void*)l, 16, 0, 0);
}

struct Cell {
  const unsigned short* A1; int lda1; int K1;
  const unsigned short* A2; int lda2; int K2;
  const unsigned short* W;  int ldw;
  const float* bias;
  float* c;
  unsigned short* h;
  float* yout; int yt;
  int N; int ngates;
};

__device__ __forceinline__ void compute_frag(const char* At, const char* Bt,
                                             f32x4 acc[2], int wm, int wn, int lane) {
#pragma unroll
  for (int ks = 0; ks < 4; ++ks) {
    int ar = wm*16 + (lane & 15);
    int as = (ks*4 + (lane >> 4)) ^ (ar & 7);
    s16x8 a = *(const s16x8*)(At + ar*256 + as*16);
#pragma unroll
    for (int nf = 0; nf < 2; ++nf) {
      int br = wn*32 + nf*16 + (lane & 15);
      int bsl = (ks*4 + (lane >> 4)) ^ (br & 7);
      s16x8 b = *(const s16x8*)(Bt + br*256 + bsl*16);
      acc[nf] = __builtin_amdgcn_mfma_f32_16x16x32_bf16(a, b, acc[nf], 0, 0, 0);
    }
  }
}

// ================= encoder kernel: round-4/7 VERBATIM =================
__global__ __launch_bounds__(256, 2) void enc_kernel(Cell ca, Cell cb, int mode)
{
  __shared__ union SM {
    struct { unsigned short A[3][BM*BK]; unsigned short Bm[3][BN*BK]; } stg; // 72KB
    float gates[BM][BN+4];
  } sm;

  const int bid = (int)blockIdx.x;
  int tm, tn; bool isB = false;
  if (mode == 0) {
    int xcd = bid & 7, j = bid >> 3;
    isB = j >= 24; int jj = isB ? j - 24 : j;
    tn = xcd * 6 + (jj >> 2); tm = jj & 3;
  } else if (mode == 2) {
    int xcd = bid & 7, j = bid >> 3;
    tn = xcd * 6 + (j >> 2); tm = j & 3;
  } else {
    tm = bid & 3; tn = bid >> 2;
  }
  const Cell C = isB ? cb : ca;
  const int b0 = tm * BM;

  const int tid  = (int)threadIdx.x;
  const int wave = tid >> 6;
  const int lane = tid & 63;
  const int wm = wave >> 1, wn = wave & 1;

  const int nit = (C.K1 + C.K2) / BK;

  f32x4 acc[2] = {{0.f,0.f,0.f,0.f},{0.f,0.f,0.f,0.f}};

  auto stage = [&](int buf, int ck) {
    int kk = ck * BK;
#pragma unroll
    for (int q = 0; q < 2; ++q) {
      int cch = wave*2 + q;
      int P = cch*1024 + lane*16;
      int r = P >> 8;
      int sl = ((P >> 4) & 15) ^ (r & 7);
      int ke = kk + sl*8;
      const unsigned short* gp = (ke < C.K1)
        ? (C.A1 + (long)(b0 + r) * C.lda1 + ke)
        : (C.A2 + (long)(b0 + r) * C.lda2 + (ke - C.K1));
      async16(gp, (char*)(sm.stg.A[buf]) + cch*1024);
    }
#pragma unroll
    for (int q = 0; q < 4; ++q) {
      int cch = wave*4 + q;
      int P = cch*1024 + lane*16;
      int r = P >> 8;
      int sl = ((P >> 4) & 15) ^ (r & 7);
      int ke = kk + sl*8;
      const unsigned short* gp = C.W + (long)(tn*BN + r) * C.ldw + ke;
      async16(gp, (char*)(sm.stg.Bm[buf]) + cch*1024);
    }
  };

  stage(0, 0);
  stage(1, 1);
  for (int it = 0; it < nit; ++it) {
    if (it + 1 < nit) asm volatile("s_waitcnt vmcnt(6)" ::: "memory");
    else              asm volatile("s_waitcnt vmcnt(0)" ::: "memory");
    __builtin_amdgcn_s_barrier();
    __builtin_amdgcn_sched_barrier(0);
    if (it + 2 < nit) stage((it + 2) % 3, it + 2);
    compute_frag((const char*)sm.stg.A[it % 3], (const char*)sm.stg.Bm[it % 3],
                 acc, wm, wn, lane);
  }

  const int gcol0 = tn * BN;
  if (gcol0 >= C.ngates) {
#pragma unroll
    for (int nf = 0; nf < 2; ++nf) {
      int col = wn*32 + nf*16 + (lane & 15);
      float bia = C.bias[gcol0 + col];
      int fo = gcol0 + col - C.ngates;
#pragma unroll
      for (int rg = 0; rg < 4; ++rg) {
        int brow = wm*16 + (lane >> 4)*4 + rg;
        C.yout[(long)(b0 + brow)*(T_*F_) + (long)C.yt*F_ + fo] = acc[nf][rg] + bia;
      }
    }
    return;
  }

  __syncthreads();
#pragma unroll
  for (int nf = 0; nf < 2; ++nf) {
    int col = wn*32 + nf*16 + (lane & 15);
#pragma unroll
    for (int rg = 0; rg < 4; ++rg) {
      int brow = wm*16 + (lane >> 4)*4 + rg;
      sm.gates[brow][col] = acc[nf][rg];
    }
  }
  __syncthreads();

  const float* bs0 = C.bias + (long)tn*BN;
  for (int e = tid; e < BM*UPT; e += 256) {
    int bl = e >> 4, ul = e & 15;
    float gi = sm.gates[bl][ 0 + ul] + bs0[ 0 + ul];
    float gf = sm.gates[bl][16 + ul] + bs0[16 + ul];
    float gg = sm.gates[bl][32 + ul] + bs0[32 + ul];
    float go = sm.gates[bl][48 + ul] + bs0[48 + ul];
    float iv = 1.f / (1.f + __expf(-gi));
    float fv = 1.f / (1.f + __expf(-gf));
    float gc = fminf(fmaxf(gg, -15.f), 15.f);
    float eg = __expf(2.f * gc);
    float gv = (eg - 1.f) / (eg + 1.f);
    float ov = 1.f / (1.f + __expf(-go));
    long ci = (long)(b0 + bl)*H_ + (long)tn*UPT + ul;
    float c2 = fv * C.c[ci] + iv * gv;
    C.c[ci] = c2;
    float cc = fminf(fmaxf(c2, -15.f), 15.f);
    float ec = __expf(2.f * cc);
    float th = (ec - 1.f) / (ec + 1.f);
    C.h[ci] = f2bf(ov * th);
  }
}

// ============ cooperative decoder: 513 phases, OFFICIAL grid.sync() ============
struct DecP {
  const unsigned short *xbf, *Wdec0f, *Wext, *Wdec1, *linWbf;
  const float *bdec0f, *bext, *bdec1, *linb;
  unsigned short *h00, *h01, *h10, *h11;
  float *c0, *c1;
  float* out;
};

__global__ __launch_bounds__(256, 1) void dec_coop(DecP P)
{
  cg::grid_group grid = cg::this_grid();

  __shared__ struct {
    char A[12][8192];                                      // 96KB full A panel
    union { char Bm[3][16384]; float gates[BM][BN+4]; } u; // 48KB
  } sm;

  const int bid = (int)blockIdx.x;
  const int tid = (int)threadIdx.x;
  const int wave = tid >> 6, lane = tid & 63;
  const int wm = wave >> 1, wn = wave & 1;

  const int xcd = bid & 7, j = bid >> 3;
  const bool isGate = (j < 24);
  const int tmg = isGate ? (j & 3) : 0;
  const int tng = isGate ? (xcd * 6 + (j >> 2)) : 0;
  const int tmy = xcd & 3, tny = 48 + (xcd >> 2);   // j==24 y-extension tiles

  unsigned short* h0e[2] = { P.h00, P.h01 };
  unsigned short* h1e[2] = { P.h10, P.h11 };

  for (int p = 0; p <= 512; ++p) {
    // ---------------- job build (round-8 verbatim, proven correct) ----------------
    const unsigned short *A1 = nullptr, *A2 = nullptr, *W = nullptr;
    const float* bias = nullptr;
    float* cst = nullptr; unsigned short* hdst = nullptr;
    float* yout = nullptr; int yt = 0;
    long lda1 = 0, lda2 = 0; int K1 = 0, K2 = 0, ldw = 0, ngates = 0;
    int tm = tmg, tn = tng;
    bool active = false;

    if (p == 512) {                               // final y(255) -> out[:,0,:]
      if (bid < 8) {
        active = true; tm = bid & 3; tn = bid >> 2;
        A1 = h1e[1]; lda1 = H_; K1 = H_; K2 = 0;
        W = P.linWbf; ldw = H_;
        bias = P.linb; ngates = 0;
        yout = P.out; yt = 0;
      }
    } else if ((p & 1) == 0) {                    // cd0(t)
      int t = p >> 1;
      if (t == 0) {
        if (isGate) {
          active = true;
          A1 = P.xbf + (long)(T_-1)*F_; lda1 = (long)T_*F_; K1 = F_;
          A2 = h0e[0]; lda2 = H_; K2 = H_;
          W = P.Wdec0f; ldw = F_+H_;
          bias = P.bdec0f; ngates = NG;
          cst = P.c0; hdst = h0e[1];
        }
      } else {
        active = true;
        if (!isGate) { tm = tmy; tn = tny; }      // y panels ride along
        A1 = h1e[(t+1)&1]; lda1 = H_; K1 = H_;    // fresh h1(t-1)
        A2 = h0e[t&1];     lda2 = H_; K2 = H_;    // h0(t-1)
        W = P.Wext; ldw = 2*H_;
        bias = P.bext; ngates = NG;
        cst = P.c0; hdst = h0e[(t+1)&1];
        yout = P.out; yt = T_ - t;
      }
    } else {                                      // cd1(t)
      int t = (p - 1) >> 1;
      if (isGate) {
        active = true;
        if (t == 0) { A1 = h0e[1]; A2 = h1e[1]; hdst = h1e[0]; }
        else        { A1 = h0e[(t+1)&1]; A2 = h1e[(t+1)&1]; hdst = h1e[t&1]; }
        lda1 = H_; K1 = H_; lda2 = H_; K2 = H_;
        W = P.Wdec1; ldw = 2*H_;
        bias = P.bdec1; ngates = NG;
        cst = P.c1;
      }
    }

    if (active) {
      const int b0 = tm * BM;
      const int nit = (K1 + K2) / BK;
      const int gcol0 = tn * BN;

      for (int ck = 0; ck < nit; ++ck) {          // full-A issue up-front
        int kk = ck * BK;
#pragma unroll
        for (int q = 0; q < 2; ++q) {
          int cch = wave*2 + q;
          int Pb = cch*1024 + lane*16;
          int r = Pb >> 8;
          int sl = ((Pb >> 4) & 15) ^ (r & 7);
          int ke = kk + sl*8;
          const unsigned short* gp = (ke < K1)
            ? (A1 + (long)(b0 + r) * lda1 + ke)
            : (A2 + (long)(b0 + r) * lda2 + (ke - K1));
          async16(gp, sm.A[ck] + cch*1024);
        }
      }
      auto stageB = [&](int buf, int ck) {
        int kk = ck * BK;
#pragma unroll
        for (int q = 0; q < 4; ++q) {
          int cch = wave*4 + q;
          int Pb = cch*1024 + lane*16;
          int r = Pb >> 8;
          int sl = ((Pb >> 4) & 15) ^ (r & 7);
          int ke = kk + sl*8;
          async16(W + (long)(tn*BN + r) * ldw + ke, sm.u.Bm[buf] + cch*1024);
        }
      };
      stageB(0, 0);
      if (nit > 1) stageB(1, 1);

      f32x4 acc[2] = {{0.f,0.f,0.f,0.f},{0.f,0.f,0.f,0.f}};
      for (int it = 0; it < nit; ++it) {
        if (it + 1 < nit) asm volatile("s_waitcnt vmcnt(4)" ::: "memory");
        else              asm volatile("s_waitcnt vmcnt(0)" ::: "memory");
        __builtin_amdgcn_s_barrier();
        __builtin_amdgcn_sched_barrier(0);
        if (it + 2 < nit) stageB((it + 2) % 3, it + 2);
        compute_frag(sm.A[it], sm.u.Bm[it % 3], acc, wm, wn, lane);
      }

      if (gcol0 >= ngates) {                      // pure y tile
#pragma unroll
        for (int nf = 0; nf < 2; ++nf) {
          int col = wn*32 + nf*16 + (lane & 15);
          float bia = bias[gcol0 + col];
          int fo = gcol0 + col - ngates;
#pragma unroll
          for (int rg = 0; rg < 4; ++rg) {
            int brow = wm*16 + (lane >> 4)*4 + rg;
            yout[(long)(b0 + brow)*(T_*F_) + (long)yt*F_ + fo] = acc[nf][rg] + bia;
          }
        }
      } else {
        __syncthreads();
#pragma unroll
        for (int nf = 0; nf < 2; ++nf) {
          int col = wn*32 + nf*16 + (lane & 15);
#pragma unroll
          for (int rg = 0; rg < 4; ++rg) {
            int brow = wm*16 + (lane >> 4)*4 + rg;
            sm.u.gates[brow][col] = acc[nf][rg];
          }
        }
        __syncthreads();
        const float* bs0 = bias + (long)tn*BN;
        for (int e = tid; e < BM*UPT; e += 256) {
          int bl = e >> 4, ul = e & 15;
          float gi = sm.u.gates[bl][ 0 + ul] + bs0[ 0 + ul];
          float gf = sm.u.gates[bl][16 + ul] + bs0[16 + ul];
          float gg = sm.u.gates[bl][32 + ul] + bs0[32 + ul];
          float go = sm.u.gates[bl][48 + ul] + bs0[48 + ul];
          float iv = 1.f / (1.f + __expf(-gi));
          float fv = 1.f / (1.f + __expf(-gf));
          float gc = fminf(fmaxf(gg, -15.f), 15.f);
          float eg = __expf(2.f * gc);
          float gv = (eg - 1.f) / (eg + 1.f);
          float ov = 1.f / (1.f + __expf(-go));
          long ci = (long)(b0 + bl)*H_ + (long)tn*UPT + ul;
          float c2 = fv * cst[ci] + iv * gv;
          cst[ci] = c2;
          float cc2 = fminf(fmaxf(c2, -15.f), 15.f);
          float ec = __expf(2.f * cc2);
          float th = (ec - 1.f) / (ec + 1.f);
          hdst[ci] = f2bf(ov * th);
        }
      }
    }

    // ---------------- OFFICIAL grid-wide barrier ----------------
    if (p < 512) grid.sync();
  }
}

// ---------------- prep kernels (proven) ----------------
__global__ void k_convx(const float* x, unsigned short* xbf, long n) {
  long st = (long)gridDim.x * 256;
  for (long i = (long)blockIdx.x*256 + threadIdx.x; i < n; i += st) xbf[i] = f2bf(x[i]);
}

__global__ void k_init(const float* h0in, const float* c0in,
                       unsigned short* h0e0, unsigned short* h1e1,
                       float* c0buf, float* c1buf) {
  int i = blockIdx.x*256 + threadIdx.x;
  if (i < B_*H_) {
    h0e0[i] = f2bf(h0in[i]);
    h1e1[i] = f2bf(h0in[B_*H_ + i]);
    c0buf[i] = c0in[i];
    c1buf[i] = c0in[B_*H_ + i];
  }
}

__global__ __launch_bounds__(256) void k_wcomb(const float* A, const float* Bm, float* Cm) {
  __shared__ float sA[16*128];
  int tid = threadIdx.x;
  int r0 = blockIdx.x * 16;
  int c0 = blockIdx.y * 128;
  for (int e = tid; e < 16*128; e += 256)
    sA[e] = A[(long)(r0 + (e >> 7))*128 + (e & 127)];
  __syncthreads();
  int col = c0 + (tid & 127);
  int rg = (tid >> 7) * 8;
  float acc[8] = {0,0,0,0,0,0,0,0};
  for (int k = 0; k < 128; ++k) {
    float b = Bm[(long)k*768 + col];
#pragma unroll
    for (int r = 0; r < 8; ++r) acc[r] += sA[(rg + r)*128 + k] * b;
  }
  for (int r = 0; r < 8; ++r) Cm[(long)(r0 + rg + r)*768 + col] = acc[r];
}

__global__ void k_bcomb(const float* dWih0, const float* linb, const float* db0, float* bc) {
  int j = blockIdx.x*256 + threadIdx.x;
  if (j < NG) {
    float s = db0[j];
    for (int f = 0; f < 128; ++f) s += dWih0[(long)j*128 + f] * linb[f];
    bc[j] = s;
  }
}

__global__ void k_pack(unsigned short* dst, float* bdst, const float* s1, int K1,
                       const float* s2, int K2, const float* bs) {
  long Kt = K1 + K2, total = (long)NG * Kt;
  long st = (long)gridDim.x * 256;
  for (long i = (long)blockIdx.x*256 + threadIdx.x; i < total; i += st) {
    int n = (int)(i / Kt), k = (int)(i % Kt);
    int tn = n >> 6, r = n & 63;
    int j = (r >> 4)*H_ + tn*UPT + (r & 15);
    float v = (k < K1) ? s1[(long)j*K1 + k] : s2[(long)j*K2 + (k - K1)];
    dst[i] = f2bf(v);
    if (k == 0) bdst[n] = bs[j];
  }
}

__global__ void k_packext(unsigned short* dst, float* bdst, const float* wcomb,
                          const float* whh0, const float* bcomb,
                          const float* linW, const float* linb) {
  long total = (long)(NG + F_) * (2*H_);
  long st = (long)gridDim.x * 256;
  for (long i = (long)blockIdx.x*256 + threadIdx.x; i < total; i += st) {
    int n = (int)(i / (2*H_)), k = (int)(i % (2*H_));
    float v;
    if (n < NG) {
      int tn = n >> 6, r = n & 63;
      int j = (r >> 4)*H_ + tn*UPT + (r & 15);
      v = (k < H_) ? wcomb[(long)j*H_ + k] : whh0[(long)j*H_ + (k - H_)];
      if (k == 0) bdst[n] = bcomb[j];
    } else {
      int f = n - NG;
      v = (k < H_) ? linW[(long)f*H_ + k] : 0.f;
      if (k == 0) bdst[n] = linb[f];
    }
    dst[i] = f2bf(v);
  }
}

__global__ void k_packlin(unsigned short* dst, const float* linW) {
  int i = blockIdx.x*256 + threadIdx.x;
  if (i < F_*H_) dst[i] = f2bf(linW[i]);
}

// ---------------- host ----------------
extern "C" void kernel_launch(void* const* d_in, const int* in_sizes, int n_in,
                              void* d_out, int out_size, void* d_ws, size_t ws_size,
                              hipStream_t stream)
{
  (void)in_sizes; (void)n_in; (void)out_size; (void)ws_size;
  const float* x     = (const float*)d_in[0];
  const float* h0in  = (const float*)d_in[1];
  const float* c0in  = (const float*)d_in[2];
  const float* eWih0 = (const float*)d_in[3];
  const float* eWhh0 = (const float*)d_in[4];
  const float* eb0   = (const float*)d_in[5];
  const float* eWih1 = (const float*)d_in[6];
  const float* eWhh1 = (const float*)d_in[7];
  const float* eb1   = (const float*)d_in[8];
  const float* dWih0 = (const float*)d_in[9];
  const float* dWhh0 = (const float*)d_in[10];
  const float* db0   = (const float*)d_in[11];
  const float* dWih1 = (const float*)d_in[12];
  const float* dWhh1 = (const float*)d_in[13];
  const float* db1   = (const float*)d_in[14];
  const float* linW  = (const float*)d_in[15];
  const float* linb  = (const float*)d_in[16];
  float* out = (float*)d_out;

  char* wp = (char*)d_ws;
  auto alloc = [&](size_t bytes) -> void* {
    void* p = (void*)wp;
    wp += (bytes + 255) & ~(size_t)255;
    return p;
  };
  unsigned short* xbf    = (unsigned short*)alloc((size_t)B_*T_*F_*2);
  unsigned short* Wenc0  = (unsigned short*)alloc((size_t)NG*(F_+H_)*2);
  unsigned short* Wenc1  = (unsigned short*)alloc((size_t)NG*(2*H_)*2);
  unsigned short* Wdec0f = (unsigned short*)alloc((size_t)NG*(F_+H_)*2);
  unsigned short* Wext   = (unsigned short*)alloc((size_t)(NG+F_)*(2*H_)*2);
  unsigned short* Wdec1  = (unsigned short*)alloc((size_t)NG*(2*H_)*2);
  unsigned short* linWbf = (unsigned short*)alloc((size_t)F_*H_*2);
  float* Wcomb = (float*)alloc((size_t)NG*H_*4);
  float* benc0 = (float*)alloc((size_t)NG*4);
  float* benc1 = (float*)alloc((size_t)NG*4);
  float* bdec0f= (float*)alloc((size_t)NG*4);
  float* bext  = (float*)alloc((size_t)(NG+F_)*4);
  float* bdec1 = (float*)alloc((size_t)NG*4);
  float* bcomb = (float*)alloc((size_t)NG*4);
  unsigned short* h0e[2];
  h0e[0] = (unsigned short*)alloc((size_t)B_*H_*2);
  h0e[1] = (unsigned short*)alloc((size_t)B_*H_*2);
  unsigned short* h1e[2];
  h1e[0] = (unsigned short*)alloc((size_t)B_*H_*2);
  h1e[1] = (unsigned short*)alloc((size_t)B_*H_*2);
  float* c0buf = (float*)alloc((size_t)B_*H_*4);
  float* c1buf = (float*)alloc((size_t)B_*H_*4);

  // ---- prep
  k_convx<<<2048, 256, 0, stream>>>(x, xbf, (long)B_*T_*F_);
  k_init<<<(B_*H_+255)/256, 256, 0, stream>>>(h0in, c0in, h0e[0], h1e[1], c0buf, c1buf);
  k_wcomb<<<dim3(192,6), 256, 0, stream>>>(dWih0, linW, Wcomb);
  k_bcomb<<<(NG+255)/256, 256, 0, stream>>>(dWih0, linb, db0, bcomb);
  k_pack<<<2048, 256, 0, stream>>>(Wenc0, benc0, eWih0, F_, eWhh0, H_, eb0);
  k_pack<<<2048, 256, 0, stream>>>(Wenc1, benc1, eWih1, H_, eWhh1, H_, eb1);
  k_pack<<<2048, 256, 0, stream>>>(Wdec0f, bdec0f, dWih0, F_, dWhh0, H_, db0);
  k_pack<<<2048, 256, 0, stream>>>(Wdec1, bdec1, dWih1, H_, dWhh1, H_, db1);
  k_packext<<<2048, 256, 0, stream>>>(Wext, bext, Wcomb, dWhh0, bcomb, linW, linb);
  k_packlin<<<(F_*H_+255)/256, 256, 0, stream>>>(linWbf, linW);

  auto mk = [&](const unsigned short* A1, int lda1, int K1,
                const unsigned short* A2, int lda2, int K2,
                const unsigned short* W, const float* bias,
                float* c, unsigned short* h, float* yo, int yt,
                int N, int ngates) {
    Cell cc; cc.A1=A1; cc.lda1=lda1; cc.K1=K1; cc.A2=A2; cc.lda2=lda2; cc.K2=K2;
    cc.W=W; cc.ldw=K1+K2; cc.bias=bias; cc.c=c; cc.h=h; cc.yout=yo; cc.yt=yt;
    cc.N=N; cc.ngates=ngates;
    return cc;
  };

  // ---- encoder: round-4/7 verbatim
  for (int s = 0; s <= T_; ++s) {
    Cell cA = {}, cB = {};
    bool hasA = (s < T_), hasB = (s >= 1);
    if (hasA)
      cA = mk(xbf + (long)s*F_, T_*F_, F_, h0e[s&1], H_, H_,
              Wenc0, benc0, c0buf, h0e[(s+1)&1], nullptr, 0, NG, NG);
    if (hasB)
      cB = mk(h0e[s&1], H_, H_, h1e[s&1], H_, H_,
              Wenc1, benc1, c1buf, h1e[(s+1)&1], nullptr, 0, NG, NG);
    if (hasA && hasB) enc_kernel<<<384, 256, 0, stream>>>(cA, cB, 0);
    else if (hasA)    enc_kernel<<<192, 256, 0, stream>>>(cA, cA, 2);
    else              enc_kernel<<<192, 256, 0, stream>>>(cB, cB, 2);
  }

  // ---- decoder: ONE cooperative kernel (513 phases incl. final y)
  DecP P;
  P.xbf = xbf; P.Wdec0f = Wdec0f; P.Wext = Wext; P.Wdec1 = Wdec1; P.linWbf = linWbf;
  P.bdec0f = bdec0f; P.bext = bext; P.bdec1 = bdec1; P.linb = linb;
  P.h00 = h0e[0]; P.h01 = h0e[1]; P.h10 = h1e[0]; P.h11 = h1e[1];
  P.c0 = c0buf; P.c1 = c1buf;
  P.out = out;
  void* args[] = { (void*)&P };
  hipLaunchCooperativeKernel((const void*)dec_coop, dim3(NB), dim3(256), args, 0, stream);
}

// Round 11
// 7048.261 us; speedup vs baseline: 2.1534x; 2.1534x over previous
//
#include <hip/hip_runtime.h>

#define B_ 128
#define T_ 256
#define F_ 128
#define H_ 768
#define NG 3072      // 4*H
#define BM 32
#define BN 64
#define BK 128
#define UPT 16       // units per N-tile = BN/4

typedef short s16x8 __attribute__((ext_vector_type(8)));
typedef float f32x4 __attribute__((ext_vector_type(4)));

__device__ __forceinline__ unsigned short f2bf(float x) {
  unsigned u = __float_as_uint(x);
  u += 0x7fffu + ((u >> 16) & 1u);
  return (unsigned short)(u >> 16);
}

__device__ __forceinline__ void async16(const void* g, void* l) {
  __builtin_amdgcn_global_load_lds(
      (const __attribute__((address_space(1))) void*)g,
      (__attribute__((address_space(3))) void*)l, 16, 0, 0);
}

struct Cell {
  const unsigned short* A1; int lda1; int K1;
  const unsigned short* A2; int lda2; int K2;
  const unsigned short* W;  int ldw;
  const float* bias;
  float* c;
  unsigned short* h;
  float* yout; int yt;
  int N; int ngates;
};

__device__ __forceinline__ void compute_frag(const char* At, const char* Bt,
                                             f32x4 acc[2], int wm, int wn, int lane) {
#pragma unroll
  for (int ks = 0; ks < 4; ++ks) {
    int ar = wm*16 + (lane & 15);
    int as = (ks*4 + (lane >> 4)) ^ (ar & 7);
    s16x8 a = *(const s16x8*)(At + ar*256 + as*16);
#pragma unroll
    for (int nf = 0; nf < 2; ++nf) {
      int br = wn*32 + nf*16 + (lane & 15);
      int bsl = (ks*4 + (lane >> 4)) ^ (br & 7);
      s16x8 b = *(const s16x8*)(Bt + br*256 + bsl*16);
      acc[nf] = __builtin_amdgcn_mfma_f32_16x16x32_bf16(a, b, acc[nf], 0, 0, 0);
    }
  }
}

// ================= encoder kernel: round-4 cell_kernel VERBATIM =================
// modes: 0 = enc dual (384 blk), 2 = generic single (192 blk), 3 = tiny y-final (8)
__global__ __launch_bounds__(256, 2) void enc_kernel(Cell ca, Cell cb, int mode)
{
  __shared__ union SM {
    struct { unsigned short A[3][BM*BK]; unsigned short Bm[3][BN*BK]; } stg; // 72KB
    float gates[BM][BN+4];
  } sm;

  const int bid = (int)blockIdx.x;
  int tm, tn; bool isB = false;
  if (mode == 0) {
    int xcd = bid & 7, j = bid >> 3;          // j 0..47
    isB = j >= 24; int jj = isB ? j - 24 : j;
    tn = xcd * 6 + (jj >> 2); tm = jj & 3;    // 4 tm-blocks of a panel share an XCD
  } else if (mode == 2) {
    int xcd = bid & 7, j = bid >> 3;          // j 0..23
    tn = xcd * 6 + (j >> 2); tm = j & 3;
  } else {
    tm = bid & 3; tn = bid >> 2;
  }
  const Cell C = isB ? cb : ca;
  const int b0 = tm * BM;

  const int tid  = (int)threadIdx.x;
  const int wave = tid >> 6;
  const int lane = tid & 63;
  const int wm = wave >> 1, wn = wave & 1;

  const int nit = (C.K1 + C.K2) / BK;

  f32x4 acc[2] = {{0.f,0.f,0.f,0.f},{0.f,0.f,0.f,0.f}};

  auto stage = [&](int buf, int ck) {
    int kk = ck * BK;
#pragma unroll
    for (int q = 0; q < 2; ++q) {            // A: 8KB
      int cch = wave*2 + q;
      int P = cch*1024 + lane*16;
      int r = P >> 8;
      int sl = ((P >> 4) & 15) ^ (r & 7);
      int ke = kk + sl*8;
      const unsigned short* gp = (ke < C.K1)
        ? (C.A1 + (long)(b0 + r) * C.lda1 + ke)
        : (C.A2 + (long)(b0 + r) * C.lda2 + (ke - C.K1));
      async16(gp, (char*)(sm.stg.A[buf]) + cch*1024);
    }
#pragma unroll
    for (int q = 0; q < 4; ++q) {            // B: 16KB
      int cch = wave*4 + q;
      int P = cch*1024 + lane*16;
      int r = P >> 8;
      int sl = ((P >> 4) & 15) ^ (r & 7);
      int ke = kk + sl*8;
      const unsigned short* gp = C.W + (long)(tn*BN + r) * C.ldw + ke;
      async16(gp, (char*)(sm.stg.Bm[buf]) + cch*1024);
    }
  };

  stage(0, 0);
  stage(1, 1);
  for (int it = 0; it < nit; ++it) {
    if (it + 1 < nit) asm volatile("s_waitcnt vmcnt(6)" ::: "memory");
    else              asm volatile("s_waitcnt vmcnt(0)" ::: "memory");
    __builtin_amdgcn_s_barrier();
    __builtin_amdgcn_sched_barrier(0);
    if (it + 2 < nit) stage((it + 2) % 3, it + 2);
    compute_frag((const char*)sm.stg.A[it % 3], (const char*)sm.stg.Bm[it % 3],
                 acc, wm, wn, lane);
  }

  const int gcol0 = tn * BN;
  if (gcol0 >= C.ngates) {
#pragma unroll
    for (int nf = 0; nf < 2; ++nf) {
      int col = wn*32 + nf*16 + (lane & 15);
      float bia = C.bias[gcol0 + col];
      int fo = gcol0 + col - C.ngates;
#pragma unroll
      for (int rg = 0; rg < 4; ++rg) {
        int brow = wm*16 + (lane >> 4)*4 + rg;
        C.yout[(long)(b0 + brow)*(T_*F_) + (long)C.yt*F_ + fo] = acc[nf][rg] + bia;
      }
    }
    return;
  }

  __syncthreads();
#pragma unroll
  for (int nf = 0; nf < 2; ++nf) {
    int col = wn*32 + nf*16 + (lane & 15);
#pragma unroll
    for (int rg = 0; rg < 4; ++rg) {
      int brow = wm*16 + (lane >> 4)*4 + rg;
      sm.gates[brow][col] = acc[nf][rg];
    }
  }
  __syncthreads();

  const float* bs0 = C.bias + (long)tn*BN;
  for (int e = tid; e < BM*UPT; e += 256) {
    int bl = e >> 4, ul = e & 15;
    float gi = sm.gates[bl][ 0 + ul] + bs0[ 0 + ul];
    float gf = sm.gates[bl][16 + ul] + bs0[16 + ul];
    float gg = sm.gates[bl][32 + ul] + bs0[32 + ul];
    float go = sm.gates[bl][48 + ul] + bs0[48 + ul];
    float iv = 1.f / (1.f + __expf(-gi));
    float fv = 1.f / (1.f + __expf(-gf));
    float gc = fminf(fmaxf(gg, -15.f), 15.f);
    float eg = __expf(2.f * gc);
    float gv = (eg - 1.f) / (eg + 1.f);
    float ov = 1.f / (1.f + __expf(-go));
    long ci = (long)(b0 + bl)*H_ + (long)tn*UPT + ul;
    float c2 = fv * C.c[ci] + iv * gv;
    C.c[ci] = c2;
    float cc = fminf(fmaxf(c2, -15.f), 15.f);
    float ec = __expf(2.f * cc);
    float th = (ec - 1.f) / (ec + 1.f);
    C.h[ci] = f2bf(ov * th);
  }
}

// ======== decoder kernel: single cell, FULL-A up-front + B 3-ring + c prefetch ========
// modes: 1 = cd0ext (200 blk, j==24 -> y panels tn 48/49), 2 = generic (192 blk)
__global__ __launch_bounds__(256, 1) void dec_kernel(Cell C, int mode)
{
  __shared__ struct SMD {
    char A[12][8192];        // 96KB: whole A panel, one chunk per K=128 slab
    char Bm[3][16384];       // 48KB: B ring
    float ctile[BM][UPT];    // 2KB: prefetched c state
    float gates[BM][BN+4];   // 8.5KB
  } sm;                      // ~155KB -> 1 block/CU

  const int bid = (int)blockIdx.x;
  const int tid = (int)threadIdx.x;
  const int wave = tid >> 6, lane = tid & 63;
  const int wm = wave >> 1, wn = wave & 1;

  int tm, tn;
  if (mode == 1) {
    int xcd = bid & 7, j = bid >> 3;
    if (j < 24) { tn = xcd*6 + (j >> 2); tm = j & 3; }
    else        { tn = 48 + (xcd >> 2); tm = xcd & 3; }   // y panels
  } else {
    int xcd = bid & 7, j = bid >> 3;
    tn = xcd*6 + (j >> 2); tm = j & 3;
  }
  const int b0 = tm * BM;
  const int nit = (C.K1 + C.K2) / BK;        // 7 or 12
  const int gcol0 = tn * BN;
  const bool hasC = (C.c != nullptr) && (gcol0 < C.ngates);

  // ---- prefetch c tile (32x16 f32, 2KB): each wave issues exactly 1 load (halves duplicated)
  if (hasC) {
    int off = (wave & 1) * 1024 + lane * 16;  // byte offset into ctile
    int r = off >> 6, cc = (off & 63) >> 2;   // 64B per row of 16 floats
    async16(C.c + (long)(b0 + r) * H_ + (long)tn * UPT + cc,
            &sm.ctile[r][cc]);
  }

  // ---- issue the ENTIRE A panel up-front: 2 loads/wave per chunk, fully parallel
  for (int ck = 0; ck < nit; ++ck) {
    int kk = ck * BK;
#pragma unroll
    for (int q = 0; q < 2; ++q) {
      int cch = wave*2 + q;
      int P = cch*1024 + lane*16;
      int r = P >> 8;
      int sl = ((P >> 4) & 15) ^ (r & 7);
      int ke = kk + sl*8;
      const unsigned short* gp = (ke < C.K1)
        ? (C.A1 + (long)(b0 + r) * C.lda1 + ke)
        : (C.A2 + (long)(b0 + r) * C.lda2 + (ke - C.K1));
      async16(gp, sm.A[ck] + cch*1024);
    }
  }

  auto stageB = [&](int buf, int ck) {
    int kk = ck * BK;
#pragma unroll
    for (int q = 0; q < 4; ++q) {
      int cch = wave*4 + q;
      int P = cch*1024 + lane*16;
      int r = P >> 8;
      int sl = ((P >> 4) & 15) ^ (r & 7);
      int ke = kk + sl*8;
      async16(C.W + (long)(tn*BN + r) * C.ldw + ke, sm.Bm[buf] + cch*1024);
    }
  };
  stageB(0, 0);
  if (nit > 1) stageB(1, 1);

  f32x4 acc[2] = {{0.f,0.f,0.f,0.f},{0.f,0.f,0.f,0.f}};
  // B ring with counted vmcnt(4): B_{it+1} (4 loads/wave) may stay in flight; all
  // A loads + c are older than B_{it}, so each wait also guarantees their completion.
  for (int it = 0; it < nit; ++it) {
    if (it + 1 < nit) asm volatile("s_waitcnt vmcnt(4)" ::: "memory");
    else              asm volatile("s_waitcnt vmcnt(0)" ::: "memory");
    __builtin_amdgcn_s_barrier();
    __builtin_amdgcn_sched_barrier(0);
    if (it + 2 < nit) stageB((it + 2) % 3, it + 2);
    compute_frag(sm.A[it], sm.Bm[it % 3], acc, wm, wn, lane);
  }

  if (gcol0 >= C.ngates) {                   // y tile: write straight to output
#pragma unroll
    for (int nf = 0; nf < 2; ++nf) {
      int col = wn*32 + nf*16 + (lane & 15);
      float bia = C.bias[gcol0 + col];
      int fo = gcol0 + col - C.ngates;
#pragma unroll
      for (int rg = 0; rg < 4; ++rg) {
        int brow = wm*16 + (lane >> 4)*4 + rg;
        C.yout[(long)(b0 + brow)*(T_*F_) + (long)C.yt*F_ + fo] = acc[nf][rg] + bia;
      }
    }
    return;
  }

  __syncthreads();
#pragma unroll
  for (int nf = 0; nf < 2; ++nf) {
    int col = wn*32 + nf*16 + (lane & 15);
#pragma unroll
    for (int rg = 0; rg < 4; ++rg) {
      int brow = wm*16 + (lane >> 4)*4 + rg;
      sm.gates[brow][col] = acc[nf][rg];
    }
  }
  __syncthreads();

  const float* bs0 = C.bias + (long)tn*BN;
  for (int e = tid; e < BM*UPT; e += 256) {
    int bl = e >> 4, ul = e & 15;
    float gi = sm.gates[bl][ 0 + ul] + bs0[ 0 + ul];
    float gf = sm.gates[bl][16 + ul] + bs0[16 + ul];
    float gg = sm.gates[bl][32 + ul] + bs0[32 + ul];
    float go = sm.gates[bl][48 + ul] + bs0[48 + ul];
    float iv = 1.f / (1.f + __expf(-gi));
    float fv = 1.f / (1.f + __expf(-gf));
    float gc = fminf(fmaxf(gg, -15.f), 15.f);
    float eg = __expf(2.f * gc);
    float gv = (eg - 1.f) / (eg + 1.f);
    float ov = 1.f / (1.f + __expf(-go));
    long ci = (long)(b0 + bl)*H_ + (long)tn*UPT + ul;
    float c2 = fv * sm.ctile[bl][ul] + iv * gv;   // c from LDS (prefetched)
    C.c[ci] = c2;
    float cc = fminf(fmaxf(c2, -15.f), 15.f);
    float ec = __expf(2.f * cc);
    float th = (ec - 1.f) / (ec + 1.f);
    C.h[ci] = f2bf(ov * th);
  }
}

// ---------------- prep kernels (proven) ----------------
__global__ void k_convx(const float* x, unsigned short* xbf, long n) {
  long st = (long)gridDim.x * 256;
  for (long i = (long)blockIdx.x*256 + threadIdx.x; i < n; i += st) xbf[i] = f2bf(x[i]);
}

__global__ void k_init(const float* h0in, const float* c0in,
                       unsigned short* h0e0, unsigned short* h1e1,
                       float* c0buf, float* c1buf) {
  int i = blockIdx.x*256 + threadIdx.x;
  if (i < B_*H_) {
    h0e0[i] = f2bf(h0in[i]);
    h1e1[i] = f2bf(h0in[B_*H_ + i]);
    c0buf[i] = c0in[i];
    c1buf[i] = c0in[B_*H_ + i];
  }
}

__global__ __launch_bounds__(256) void k_wcomb(const float* A, const float* Bm, float* Cm) {
  __shared__ float sA[16*128];
  int tid = threadIdx.x;
  int r0 = blockIdx.x * 16;
  int c0 = blockIdx.y * 128;
  for (int e = tid; e < 16*128; e += 256)
    sA[e] = A[(long)(r0 + (e >> 7))*128 + (e & 127)];
  __syncthreads();
  int col = c0 + (tid & 127);
  int rg = (tid >> 7) * 8;
  float acc[8] = {0,0,0,0,0,0,0,0};
  for (int k = 0; k < 128; ++k) {
    float b = Bm[(long)k*768 + col];
#pragma unroll
    for (int r = 0; r < 8; ++r) acc[r] += sA[(rg + r)*128 + k] * b;
  }
  for (int r = 0; r < 8; ++r) Cm[(long)(r0 + rg + r)*768 + col] = acc[r];
}

__global__ void k_bcomb(const float* dWih0, const float* linb, const float* db0, float* bc) {
  int j = blockIdx.x*256 + threadIdx.x;
  if (j < NG) {
    float s = db0[j];
    for (int f = 0; f < 128; ++f) s += dWih0[(long)j*128 + f] * linb[f];
    bc[j] = s;
  }
}

__global__ void k_pack(unsigned short* dst, float* bdst, const float* s1, int K1,
                       const float* s2, int K2, const float* bs) {
  long Kt = K1 + K2, total = (long)NG * Kt;
  long st = (long)gridDim.x * 256;
  for (long i = (long)blockIdx.x*256 + threadIdx.x; i < total; i += st) {
    int n = (int)(i / Kt), k = (int)(i % Kt);
    int tn = n >> 6, r = n & 63;
    int j = (r >> 4)*H_ + tn*UPT + (r & 15);
    float v = (k < K1) ? s1[(long)j*K1 + k] : s2[(long)j*K2 + (k - K1)];
    dst[i] = f2bf(v);
    if (k == 0) bdst[n] = bs[j];
  }
}

__global__ void k_packext(unsigned short* dst, float* bdst, const float* wcomb,
                          const float* whh0, const float* bcomb,
                          const float* linW, const float* linb) {
  long total = (long)(NG + F_) * (2*H_);
  long st = (long)gridDim.x * 256;
  for (long i = (long)blockIdx.x*256 + threadIdx.x; i < total; i += st) {
    int n = (int)(i / (2*H_)), k = (int)(i % (2*H_));
    float v;
    if (n < NG) {
      int tn = n >> 6, r = n & 63;
      int j = (r >> 4)*H_ + tn*UPT + (r & 15);
      v = (k < H_) ? wcomb[(long)j*H_ + k] : whh0[(long)j*H_ + (k - H_)];
      if (k == 0) bdst[n] = bcomb[j];
    } else {
      int f = n - NG;
      v = (k < H_) ? linW[(long)f*H_ + k] : 0.f;
      if (k == 0) bdst[n] = linb[f];
    }
    dst[i] = f2bf(v);
  }
}

__global__ void k_packlin(unsigned short* dst, const float* linW) {
  int i = blockIdx.x*256 + threadIdx.x;
  if (i < F_*H_) dst[i] = f2bf(linW[i]);
}

// ---------------- host ----------------
extern "C" void kernel_launch(void* const* d_in, const int* in_sizes, int n_in,
                              void* d_out, int out_size, void* d_ws, size_t ws_size,
                              hipStream_t stream)
{
  (void)in_sizes; (void)n_in; (void)out_size; (void)ws_size;
  const float* x     = (const float*)d_in[0];
  const float* h0in  = (const float*)d_in[1];
  const float* c0in  = (const float*)d_in[2];
  const float* eWih0 = (const float*)d_in[3];
  const float* eWhh0 = (const float*)d_in[4];
  const float* eb0   = (const float*)d_in[5];
  const float* eWih1 = (const float*)d_in[6];
  const float* eWhh1 = (const float*)d_in[7];
  const float* eb1   = (const float*)d_in[8];
  const float* dWih0 = (const float*)d_in[9];
  const float* dWhh0 = (const float*)d_in[10];
  const float* db0   = (const float*)d_in[11];
  const float* dWih1 = (const float*)d_in[12];
  const float* dWhh1 = (const float*)d_in[13];
  const float* db1   = (const float*)d_in[14];
  const float* linW  = (const float*)d_in[15];
  const float* linb  = (const float*)d_in[16];
  float* out = (float*)d_out;

  char* wp = (char*)d_ws;
  auto alloc = [&](size_t bytes) -> void* {
    void* p = (void*)wp;
    wp += (bytes + 255) & ~(size_t)255;
    return p;
  };
  unsigned short* xbf    = (unsigned short*)alloc((size_t)B_*T_*F_*2);
  unsigned short* Wenc0  = (unsigned short*)alloc((size_t)NG*(F_+H_)*2);
  unsigned short* Wenc1  = (unsigned short*)alloc((size_t)NG*(2*H_)*2);
  unsigned short* Wdec0f = (unsigned short*)alloc((size_t)NG*(F_+H_)*2);
  unsigned short* Wext   = (unsigned short*)alloc((size_t)(NG+F_)*(2*H_)*2);
  unsigned short* Wdec1  = (unsigned short*)alloc((size_t)NG*(2*H_)*2);
  unsigned short* linWbf = (unsigned short*)alloc((size_t)F_*H_*2);
  float* Wcomb = (float*)alloc((size_t)NG*H_*4);
  float* benc0 = (float*)alloc((size_t)NG*4);
  float* benc1 = (float*)alloc((size_t)NG*4);
  float* bdec0f= (float*)alloc((size_t)NG*4);
  float* bext  = (float*)alloc((size_t)(NG+F_)*4);
  float* bdec1 = (float*)alloc((size_t)NG*4);
  float* bcomb = (float*)alloc((size_t)NG*4);
  unsigned short* h0e[2];
  h0e[0] = (unsigned short*)alloc((size_t)B_*H_*2);
  h0e[1] = (unsigned short*)alloc((size_t)B_*H_*2);
  unsigned short* h1e[2];
  h1e[0] = (unsigned short*)alloc((size_t)B_*H_*2);
  h1e[1] = (unsigned short*)alloc((size_t)B_*H_*2);
  float* c0buf = (float*)alloc((size_t)B_*H_*4);
  float* c1buf = (float*)alloc((size_t)B_*H_*4);

  // ---- prep
  k_convx<<<2048, 256, 0, stream>>>(x, xbf, (long)B_*T_*F_);
  k_init<<<(B_*H_+255)/256, 256, 0, stream>>>(h0in, c0in, h0e[0], h1e[1], c0buf, c1buf);
  k_wcomb<<<dim3(192,6), 256, 0, stream>>>(dWih0, linW, Wcomb);
  k_bcomb<<<(NG+255)/256, 256, 0, stream>>>(dWih0, linb, db0, bcomb);
  k_pack<<<2048, 256, 0, stream>>>(Wenc0, benc0, eWih0, F_, eWhh0, H_, eb0);
  k_pack<<<2048, 256, 0, stream>>>(Wenc1, benc1, eWih1, H_, eWhh1, H_, eb1);
  k_pack<<<2048, 256, 0, stream>>>(Wdec0f, bdec0f, dWih0, F_, dWhh0, H_, db0);
  k_pack<<<2048, 256, 0, stream>>>(Wdec1, bdec1, dWih1, H_, dWhh1, H_, db1);
  k_packext<<<2048, 256, 0, stream>>>(Wext, bext, Wcomb, dWhh0, bcomb, linW, linb);
  k_packlin<<<(F_*H_+255)/256, 256, 0, stream>>>(linWbf, linW);

  auto mk = [&](const unsigned short* A1, int lda1, int K1,
                const unsigned short* A2, int lda2, int K2,
                const unsigned short* W, const float* bias,
                float* c, unsigned short* h, float* yo, int yt,
                int N, int ngates) {
    Cell cc; cc.A1=A1; cc.lda1=lda1; cc.K1=K1; cc.A2=A2; cc.lda2=lda2; cc.K2=K2;
    cc.W=W; cc.ldw=K1+K2; cc.bias=bias; cc.c=c; cc.h=h; cc.yout=yo; cc.yt=yt;
    cc.N=N; cc.ngates=ngates;
    return cc;
  };

  // ---- encoder: stage s runs enc-layer0(t=s) and enc-layer1(t=s-1) (round-4 verbatim)
  for (int s = 0; s <= T_; ++s) {
    Cell cA = {}, cB = {};
    bool hasA = (s < T_), hasB = (s >= 1);
    if (hasA)
      cA = mk(xbf + (long)s*F_, T_*F_, F_, h0e[s&1], H_, H_,
              Wenc0, benc0, c0buf, h0e[(s+1)&1], nullptr, 0, NG, NG);
    if (hasB)
      cB = mk(h0e[s&1], H_, H_, h1e[s&1], H_, H_,
              Wenc1, benc1, c1buf, h1e[(s+1)&1], nullptr, 0, NG, NG);
    if (hasA && hasB) enc_kernel<<<384, 256, 0, stream>>>(cA, cB, 0);
    else if (hasA)    enc_kernel<<<192, 256, 0, stream>>>(cA, cA, 2);
    else              enc_kernel<<<192, 256, 0, stream>>>(cB, cB, 2);
  }

  // ---- decoder: two launches per t with the full-A dec_kernel
  {
    Cell c0f = mk(xbf + (long)(T_-1)*F_, T_*F_, F_, h0e[0], H_, H_,
                  Wdec0f, bdec0f, c0buf, h0e[1], nullptr, 0, NG, NG);
    dec_kernel<<<192, 256, 0, stream>>>(c0f, 2);
    Cell c10 = mk(h0e[1], H_, H_, h1e[1], H_, H_,
                  Wdec1, bdec1, c1buf, h1e[0], nullptr, 0, NG, NG);
    dec_kernel<<<192, 256, 0, stream>>>(c10, 2);
  }
  for (int t = 1; t < T_; ++t) {
    Cell cd0 = mk(h1e[(t+1)&1], H_, H_, h0e[t&1], H_, H_,
                  Wext, bext, c0buf, h0e[(t+1)&1], out, T_-t, NG+F_, NG);
    dec_kernel<<<200, 256, 0, stream>>>(cd0, 1);
    Cell cd1 = mk(h0e[(t+1)&1], H_, H_, h1e[(t+1)&1], H_, H_,
                  Wdec1, bdec1, c1buf, h1e[t&1], nullptr, 0, NG, NG);
    dec_kernel<<<192, 256, 0, stream>>>(cd1, 2);
  }
  {
    Cell cy = mk(h1e[1], H_, H_, h1e[1], H_, 0,
                 linWbf, linb, nullptr, nullptr, out, 0, F_, 0);
    enc_kernel<<<8, 256, 0, stream>>>(cy, cy, 3);
  }
}